// Round 10
// baseline (669.494 us; speedup 1.0000x reference)
//
#include <hip/hip_runtime.h>
#include <cstdint>
#include <cstddef>

// ---------------- types ----------------
typedef __attribute__((ext_vector_type(8))) _Float16 half8;   // MFMA f16 A/B frag (4 VGPRs)
typedef __attribute__((ext_vector_type(4))) _Float16 half4;
typedef __attribute__((ext_vector_type(4))) float    floatx4; // MFMA C/D frag

static constexpr int B_ROWS = 16384;
static constexpr int IN_DIM = 256;
static constexpr int H_DIM  = 512;
static constexpr int NB     = 16;

__device__ __forceinline__ float fast_tanh(float x) {
  float ax = fabsf(x);
  float e  = __expf(2.0f * ax);             // e >= 1, inf-safe
  float t  = 1.0f - 2.0f / (e + 1.0f);
  return copysignf(t, x);
}

// ---------------- prep: x column-stats partials (blocks 0..127) + coeff cvt ----------------
// cvt folds K_n = exp(-2 c_n^2) into the fp16 coeffs; [o][k] row-major.
__global__ __launch_bounds__(256) void prep_k(const float* __restrict__ c1, _Float16* __restrict__ d1,
                                              const float* __restrict__ c2, _Float16* __restrict__ d2,
                                              const float* __restrict__ X,
                                              float* __restrict__ psx, float* __restrict__ psx2) {
  const int bx = blockIdx.x;
  if (bx < 128) {
    int c     = (bx & 3) * 64 + (threadIdx.x & 63);
    int chunk = threadIdx.x >> 6;
    int seg   = bx >> 2;
    int r0    = seg * 512;
    double s = 0.0, s2 = 0.0;
    for (int r = r0 + chunk; r < r0 + 512; r += 4) {
      float v = X[(size_t)r * IN_DIM + c];
      s += v; s2 += (double)v * (double)v;
    }
    __shared__ float Ls[256], Ls2[256];
    Ls[threadIdx.x] = (float)s; Ls2[threadIdx.x] = (float)s2;
    __syncthreads();
    if (chunk == 0) {
      int cl = threadIdx.x;
      psx [(size_t)seg * IN_DIM + c] = Ls[cl]  + Ls[cl + 64]  + Ls[cl + 128]  + Ls[cl + 192];
      psx2[(size_t)seg * IN_DIM + c] = Ls2[cl] + Ls2[cl + 64] + Ls2[cl + 128] + Ls2[cl + 192];
    }
  } else {
    const size_t n41 = (size_t)H_DIM * IN_DIM * NB / 4;
    const size_t n42 = (size_t)H_DIM * H_DIM * NB / 4;
    size_t tot = n41 + n42;
    int nb_blocks = gridDim.x - 128;
    for (size_t i = (size_t)(bx - 128) * 256 + threadIdx.x; i < tot;
         i += (size_t)nb_blocks * 256) {
      const float4* sp; half4* dp; size_t j;
      if (i < n41) { sp = (const float4*)c1; dp = (half4*)d1; j = i; }
      else         { sp = (const float4*)c2; dp = (half4*)d2; j = i - n41; }
      float4 v = sp[j];
      int nb = (int)((j << 2) & 15);
      half4 r;
      float e0 = -2.f + (float)(nb + 0) * (4.f / 15.f);
      float e1 = -2.f + (float)(nb + 1) * (4.f / 15.f);
      float e2 = -2.f + (float)(nb + 2) * (4.f / 15.f);
      float e3 = -2.f + (float)(nb + 3) * (4.f / 15.f);
      r[0] = (_Float16)(v.x * __expf(-2.f * e0 * e0));
      r[1] = (_Float16)(v.y * __expf(-2.f * e1 * e1));
      r[2] = (_Float16)(v.z * __expf(-2.f * e2 * e2));
      r[3] = (_Float16)(v.w * __expf(-2.f * e3 * e3));
      dp[j] = r;
    }
  }
}

// ---------------- fused stats-finalize+normalize+expand+GEMM+tanh + next-layer partials ----
// Proven mechanisms only: A via ds_write LDS dbuf (R7/R8), B per-lane global->VGPR (R8),
// one barrier per BK=64 super-step (2 MFMA sub-steps) — halves barrier count and gives every
// load a full super-step (~1242 cyc MFMA) to complete before its drain -> residue ~0.
// In-block stats finalize (float partials -> LDS mu/isd) removes the stats_final dispatches.
// 128x128 tile, 256 threads (2x2 waves), grid (128,4) = 512 blocks = 2 blocks/CU.
__global__ __launch_bounds__(256, 2) void kan_gemm_fused(const float* __restrict__ X,     // [B, C]
                                                         const float* __restrict__ psin,  // [segs, C]
                                                         const float* __restrict__ psin2, // [segs, C]
                                                         int segs,
                                                         const _Float16* __restrict__ Bm, // [512, C*16]
                                                         float* __restrict__ Hout,        // [B, 512]
                                                         float* __restrict__ psum,        // [128, 512]
                                                         float* __restrict__ psum2,       // [128, 512]
                                                         int C) {
  const int K = C << 4;
  const int supers = C >> 2;                // BK = 64 (4 features/super); 64 or 128 (even)
  __shared__ __align__(16) _Float16 As[2][128 * 64];   // 16 KB each; chunk = kseg*128 + row
  __shared__ float muL[512], isdL[512];
  __shared__ float Rs1[2][128], Rs2[2][128];
  const int tid = threadIdx.x;
  const int w = tid >> 6, lane = tid & 63;
  const int wm = w & 1, wn = w >> 1;        // 2x2 wave grid
  const int lrow = lane & 15, quad = lane >> 4;
  const int row0 = blockIdx.x * 128, col0 = blockIdx.y * 128;

  // ---- block-local stats finalize (deterministic fixed-order float sums)
  for (int c = tid; c < C; c += 256) {
    float s = 0.f, s2 = 0.f;
    for (int g = 0; g < segs; g++) { s += psin[(size_t)g * C + c]; s2 += psin2[(size_t)g * C + c]; }
    float mean = s / (float)B_ROWS;
    float var  = (s2 - s * s / (float)B_ROWS) / (float)(B_ROWS - 1);   // ddof=1
    var = fmaxf(var, 0.f);
    muL[c]  = mean;
    isdL[c] = 1.f / (sqrtf(var) + 1e-6f);
  }
  __syncthreads();

  // ---- A expansion mapping: thread (erow=tid>>1, eh=tid&1) stages local features eh, eh+2
  const int erow = tid >> 1, eh = tid & 1;
  const float* xp = X + (size_t)(row0 + erow) * C + eh;   // feature 4k+eh at xp[4k]
  _Float16* a0[2] = { &As[0][((2 * eh) * 128 + erow) * 8],
                      &As[1][((2 * eh) * 128 + erow) * 8] };      // ksegs 2eh, 2eh+1
  _Float16* a1[2] = { &As[0][((2 * eh + 4) * 128 + erow) * 8],
                      &As[1][((2 * eh + 4) * 128 + erow) * 8] };  // ksegs 2eh+4, 2eh+5

  auto expand2 = [&](float v, int ci, _Float16* dst) {
    float xn = fminf(fmaxf((v - muL[ci]) * isdL[ci], -3.f), 3.f);
    float Wv = __expf(-2.f * xn * xn - 8.f * xn);
    float g  = __expf((16.f / 15.f) * xn);
    half8 h0, h1; float p = Wv;
#pragma unroll
    for (int n = 0; n < 8; n++) { h0[n] = (_Float16)p; p *= g; }
#pragma unroll
    for (int n = 0; n < 8; n++) { h1[n] = (_Float16)p; p *= g; }
    *(half8*)dst          = h0;
    *(half8*)(dst + 1024) = h1;           // next kseg (+128 chunks)
  };

  // ---- B per-lane base (row-major [o][K]); frag (t, half h) at +t*16*K + super*64 + h*32
  const _Float16* bp = Bm + (size_t)(col0 + wn * 64 + lrow) * K + quad * 8;

  floatx4 acc[4][4] = {};
  half8 bA[8], bB[8];

  // ---- prologue: B super 0, A super 0; xv holds features for super 1
#pragma unroll
  for (int t = 0; t < 4; t++) {
    bA[t]     = *(const half8*)(bp + (size_t)t * 16 * K);
    bA[4 + t] = *(const half8*)(bp + (size_t)t * 16 * K + 32);
  }
  expand2(xp[0], eh, a0[0]);
  expand2(xp[2], eh + 2, a1[0]);
  float xv0 = xp[4], xv1 = xp[6];
  __syncthreads();

  auto super_body = [&](int k, half8* cur, half8* nxt, int buf) {
    if (k + 1 < supers) {
      size_t koff = (size_t)(k + 1) * 64;
#pragma unroll
      for (int t = 0; t < 4; t++) {
        nxt[t]     = *(const half8*)(bp + (size_t)t * 16 * K + koff);
        nxt[4 + t] = *(const half8*)(bp + (size_t)t * 16 * K + koff + 32);
      }
      int fb = 4 * (k + 1);
      expand2(xv0, fb + eh, a0[buf ^ 1]);
      expand2(xv1, fb + eh + 2, a1[buf ^ 1]);
      if (k + 2 < supers) { xv0 = xp[4 * (k + 2)]; xv1 = xp[4 * (k + 2) + 2]; }
    }
    half8 af[4];
#pragma unroll
    for (int t = 0; t < 4; t++)
      af[t] = *(const half8*)&As[buf][((quad) * 128 + wm * 64 + t * 16 + lrow) * 8];
#pragma unroll
    for (int tm = 0; tm < 4; tm++)
#pragma unroll
      for (int tn = 0; tn < 4; tn++)
        acc[tm][tn] = __builtin_amdgcn_mfma_f32_16x16x32_f16(af[tm], cur[tn], acc[tm][tn], 0, 0, 0);
#pragma unroll
    for (int t = 0; t < 4; t++)
      af[t] = *(const half8*)&As[buf][((4 + quad) * 128 + wm * 64 + t * 16 + lrow) * 8];
#pragma unroll
    for (int tm = 0; tm < 4; tm++)
#pragma unroll
      for (int tn = 0; tn < 4; tn++)
        acc[tm][tn] = __builtin_amdgcn_mfma_f32_16x16x32_f16(af[tm], cur[4 + tn], acc[tm][tn], 0, 0, 0);
    __syncthreads();
  };

  for (int k = 0; k < supers; k += 2) {     // supers even (64 / 128)
    super_body(k,     bA, bB, 0);
    super_body(k + 1, bB, bA, 1);
  }

  // ---- epilogue: C/D layout col=lane&15, row=quad*4+reg; fused tanh + column partial sums ----
  float s1[4] = {0.f, 0.f, 0.f, 0.f}, s2v[4] = {0.f, 0.f, 0.f, 0.f};
#pragma unroll
  for (int tm = 0; tm < 4; tm++) {
#pragma unroll
    for (int tn = 0; tn < 4; tn++) {
      int gcol = col0 + wn * 64 + tn * 16 + lrow;
#pragma unroll
      for (int r = 0; r < 4; r++) {
        int grow = row0 + wm * 64 + tm * 16 + quad * 4 + r;
        float v = fast_tanh(acc[tm][tn][r]);
        Hout[(size_t)grow * H_DIM + gcol] = v;
        s1[tn] += v; s2v[tn] += v * v;
      }
    }
  }
#pragma unroll
  for (int tn = 0; tn < 4; tn++) {
    s1[tn]  += __shfl_xor(s1[tn], 16);  s1[tn]  += __shfl_xor(s1[tn], 32);
    s2v[tn] += __shfl_xor(s2v[tn], 16); s2v[tn] += __shfl_xor(s2v[tn], 32);
  }
  if (quad == 0) {
#pragma unroll
    for (int tn = 0; tn < 4; tn++) {
      Rs1[wm][wn * 64 + tn * 16 + lrow] = s1[tn];
      Rs2[wm][wn * 64 + tn * 16 + lrow] = s2v[tn];
    }
  }
  __syncthreads();
  if (tid < 128) {
    psum [(size_t)blockIdx.x * H_DIM + col0 + tid] = Rs1[0][tid] + Rs1[1][tid];
    psum2[(size_t)blockIdx.x * H_DIM + col0 + tid] = Rs2[0][tid] + Rs2[1][tid];
  }
}

// ---------------- layer 3 (out dim 1) + skip, fp32; in-block stats finalize ----------------
// grid 256 blocks x 64 rows (4 waves x 16 rows) — fewer blocks => less redundant stats read.
__global__ __launch_bounds__(256) void layer3_k(const float* __restrict__ H2,
                                                const float* __restrict__ psin,   // [128, 512]
                                                const float* __restrict__ psin2,
                                                const float* __restrict__ C3,
                                                const float* __restrict__ X,
                                                const float* __restrict__ SW,
                                                const float* __restrict__ SB,
                                                float* __restrict__ OUT) {
  __shared__ float muL[H_DIM], isdL[H_DIM];
  int tid = threadIdx.x;
  for (int c = tid; c < H_DIM; c += 256) {
    float s = 0.f, s2 = 0.f;
    for (int g = 0; g < 128; g++) { s += psin[(size_t)g * H_DIM + c]; s2 += psin2[(size_t)g * H_DIM + c]; }
    float mean = s / (float)B_ROWS;
    float var  = (s2 - s * s / (float)B_ROWS) / (float)(B_ROWS - 1);
    var = fmaxf(var, 0.f);
    muL[c]  = mean;
    isdL[c] = 1.f / (sqrtf(var) + 1e-6f);
  }
  __syncthreads();

  int w = tid >> 6, lane = tid & 63;
  float Kn[NB];
#pragma unroll
  for (int n = 0; n < NB; n++) {
    float c = -2.f + (float)n * (4.f / 15.f);
    Kn[n] = __expf(-2.f * c * c);
  }
  float sb0 = SB[0];
  int row_base = blockIdx.x * 64 + w * 16;
  for (int r = 0; r < 16; r++) {
    int row = row_base + r;
    float s = 0.f;
#pragma unroll
    for (int j = 0; j < 8; j++) {
      int i = lane + 64 * j;
      float hv = H2[(size_t)row * H_DIM + i];
      float xn = fminf(fmaxf((hv - muL[i]) * isdL[i], -3.f), 3.f);
      float Wf = __expf(-2.f * xn * xn - 8.f * xn);
      float gf = __expf((16.f / 15.f) * xn);
      const floatx4* cp = (const floatx4*)(C3 + (size_t)i * NB);
      floatx4 c0 = cp[0], c1 = cp[1], c2 = cp[2], c3 = cp[3];
      float p = Wf;
#pragma unroll
      for (int n = 0; n < 4; n++) { s += p * Kn[n]      * c0[n]; p *= gf; }
#pragma unroll
      for (int n = 0; n < 4; n++) { s += p * Kn[n + 4]  * c1[n]; p *= gf; }
#pragma unroll
      for (int n = 0; n < 4; n++) { s += p * Kn[n + 8]  * c2[n]; p *= gf; }
#pragma unroll
      for (int n = 0; n < 4; n++) { s += p * Kn[n + 12] * c3[n]; p *= gf; }
    }
#pragma unroll
    for (int j = 0; j < 4; j++) {
      int i = lane + 64 * j;
      s += X[(size_t)row * IN_DIM + i] * SW[i];
    }
#pragma unroll
    for (int off = 32; off > 0; off >>= 1) s += __shfl_down(s, off);
    if (lane == 0) OUT[row] = s + sb0;
  }
}

// ---------------- launcher: 4 dispatches ----------------
extern "C" void kernel_launch(void* const* d_in, const int* in_sizes, int n_in,
                              void* d_out, int out_size, void* d_ws, size_t ws_size,
                              hipStream_t stream) {
  const float* x  = (const float*)d_in[0];   // [16384, 256]
  const float* c1 = (const float*)d_in[1];   // [512, 256, 16]
  const float* c2 = (const float*)d_in[2];   // [512, 512, 16]
  const float* c3 = (const float*)d_in[3];   // [1, 512, 16]
  const float* sw = (const float*)d_in[4];   // [1, 256]
  const float* sb = (const float*)d_in[5];   // [1]
  float* out = (float*)d_out;

  const int B = B_ROWS, IN = IN_DIM, H = H_DIM;

  char* ws = (char*)d_ws;
  size_t off = 0;
  auto alloc = [&](size_t bytes) -> void* {
    void* p = ws + off;
    off += (bytes + 255) & ~(size_t)255;
    return p;
  };
  _Float16* C1h = (_Float16*)alloc((size_t)H * IN * NB * 2);  //  4 MB
  _Float16* C2h = (_Float16*)alloc((size_t)H * H  * NB * 2);  //  8 MB
  float* H1  = (float*)alloc((size_t)B * H * 4);              // 32 MB
  float* H2  = (float*)alloc((size_t)B * H * 4);              // 32 MB
  float* psx  = (float*)alloc(32 * 256 * 4);                  // x-stats partials
  float* psx2 = (float*)alloc(32 * 256 * 4);
  float* psA  = (float*)alloc(128 * 512 * 4);                 // H1 partials (written by gemm1)
  float* psA2 = (float*)alloc(128 * 512 * 4);
  float* psB  = (float*)alloc(128 * 512 * 4);                 // H2 partials (written by gemm2)
  float* psB2 = (float*)alloc(128 * 512 * 4);

  // 1) prep: x-stats partials + coeff cvt
  prep_k<<<128 + 1024, 256, 0, stream>>>(c1, C1h, c2, C2h, x, psx, psx2);

  // 2) layer 1 (C=256, K=4096): finalize x-stats in-block; emit H1 partials
  kan_gemm_fused<<<dim3(B / 128, 4), 256, 0, stream>>>(x, psx, psx2, 32, C1h, H1, psA, psA2, IN);

  // 3) layer 2 (C=512, K=8192): finalize H1-stats in-block; emit H2 partials
  kan_gemm_fused<<<dim3(B / 128, 4), 256, 0, stream>>>(H1, psA, psA2, 128, C2h, H2, psB, psB2, H);

  // 4) layer 3 + skip: finalize H2-stats in-block
  layer3_k<<<B / 64, 256, 0, stream>>>(H2, psB, psB2, c3, x, sw, sb, out);
}